// Round 1
// baseline (42.667 us; speedup 1.0000x reference)
//
#include <hip/hip_runtime.h>

#define B_    64
#define KDIM  2304
#define NCOL  1470
#define NCELL 3136   // 64 * 7 * 7
#define CPAD  1536   // padded col stride for split-K partials

// ---------------------------------------------------------------------------
// GEMM: act[row][col] = sum_k x[row][k] * W[col][k]   (bias added in combine)
// Split-K: grid = (12 col-tiles of 128, splitK). Block 256 threads.
// Per-thread micro-tile: 8 rows x 4 cols.
// ---------------------------------------------------------------------------
__global__ __launch_bounds__(256) void gemm_splitk(
    const float* __restrict__ x, const float* __restrict__ W,
    float* __restrict__ partial, int kChunk)
{
    __shared__ float sx[16 * 68];    // sx[kk][row], row stride 68 (bank-spread, f4-aligned)
    __shared__ float sw[16 * 132];   // sw[kk][col], col stride 132

    const int t  = threadIdx.x;
    const int c0 = blockIdx.x * 128;
    const int k0 = blockIdx.y * kChunk;
    const int r0 = (t >> 5) << 3;    // 0,8,...,56
    const int c4 = (t & 31) << 2;    // 0,4,...,124

    float acc[8][4];
#pragma unroll
    for (int i = 0; i < 8; ++i)
#pragma unroll
        for (int j = 0; j < 4; ++j) acc[i][j] = 0.f;

    const int stages = kChunk >> 4;
    const int kk0 = t & 15;
    const int g0  = t >> 4;          // 0..15

    for (int s = 0; s < stages; ++s) {
        const int kb = k0 + (s << 4);
#pragma unroll
        for (int p = 0; p < 4; ++p) {
            int row = p * 16 + g0;
            sx[kk0 * 68 + row] = x[row * KDIM + kb + kk0];
        }
#pragma unroll
        for (int p = 0; p < 8; ++p) {
            int col = p * 16 + g0;
            int gc  = c0 + col;
            if (gc >= NCOL) gc = NCOL - 1;   // clamp; garbage cols ignored later
            sw[kk0 * 132 + col] = W[(size_t)gc * KDIM + kb + kk0];
        }
        __syncthreads();
#pragma unroll
        for (int kk = 0; kk < 16; ++kk) {
            const float4 a0 = *(const float4*)&sx[kk * 68 + r0];
            const float4 a1 = *(const float4*)&sx[kk * 68 + r0 + 4];
            const float4 w4 = *(const float4*)&sw[kk * 132 + c4];
            const float av[8] = {a0.x, a0.y, a0.z, a0.w, a1.x, a1.y, a1.z, a1.w};
            const float wv[4] = {w4.x, w4.y, w4.z, w4.w};
#pragma unroll
            for (int i = 0; i < 8; ++i)
#pragma unroll
                for (int j = 0; j < 4; ++j)
                    acc[i][j] = fmaf(av[i], wv[j], acc[i][j]);
        }
        __syncthreads();
    }

    float* pb = partial + (size_t)blockIdx.y * (B_ * CPAD) + c0 + c4;
#pragma unroll
    for (int i = 0; i < 8; ++i) {
        float4 v = make_float4(acc[i][0], acc[i][1], acc[i][2], acc[i][3]);
        *(float4*)&pb[(size_t)(r0 + i) * CPAD] = v;
    }
}

// ---------------------------------------------------------------------------
// Combine split-K partials + bias -> act (64 x 1470)
// ---------------------------------------------------------------------------
__global__ void combine_bias(const float* __restrict__ partial,
                             const float* __restrict__ bias,
                             float* __restrict__ act, int splitK)
{
    int idx = blockIdx.x * 256 + threadIdx.x;
    if (idx >= B_ * NCOL) return;
    int row = idx / NCOL;
    int col = idx - row * NCOL;
    float s = 0.f;
    for (int k = 0; k < splitK; ++k)
        s += partial[(size_t)k * (B_ * CPAD) + (size_t)row * CPAD + col];
    act[idx] = s + bias[col];
}

// ---------------------------------------------------------------------------
// Per-cell decode: class argmax, per-slot box algebra, score, validity.
// ---------------------------------------------------------------------------
__global__ void prep_cells(const float* __restrict__ act,
                           float* __restrict__ boxes,
                           float* __restrict__ scores,
                           int* __restrict__ valid)
{
    int n = blockIdx.x * 256 + threadIdx.x;
    if (n >= NCELL) return;
    const float* a = act + (size_t)n * 30;

    float mv = a[10];
    int   mi = 0;
#pragma unroll
    for (int j = 1; j < 20; ++j) {
        float v = a[10 + j];
        if (v > mv) { mv = v; mi = j; }    // strict > => first-index tie-break
    }
    float lp = (float)mi;

    int gx = n % 7;
    int gy = (n / 7) % 7;
    const float cell = (float)(1.0 / 7.0);
    float nx = (float)gx * cell;
    float ny = (float)gy * cell;

#pragma unroll
    for (int s = 0; s < 2; ++s) {
        int off = 5 * s;
        float bx0 = a[off + 0], bx1 = a[off + 1];
        float w_  = a[off + 2], h_  = a[off + 3];
        float sc  = a[off + 5];                 // faithful port: off+5
        float cx = bx0 * cell + nx;
        float cy = bx1 * cell + ny;
        float X1 = cx - 0.5f * w_;
        float Y1 = cy - 0.5f * h_;
        float X2 = cx + 0.5f * w_;
        float Y2 = cy + 0.5f * h_;
        float b0 = X1 - 0.5f * X2;
        float b1 = Y1 - 0.5f * Y2;
        float b2 = X1 + 0.5f * X2;
        float b3 = Y1 + 0.5f * Y2;
        int m = s * NCELL + n;
        boxes[m * 4 + 0] = b0;
        boxes[m * 4 + 1] = b1;
        boxes[m * 4 + 2] = b2;
        boxes[m * 4 + 3] = b3;
        scores[m] = sc;
        valid[m]  = (sc * lp > 0.5f) ? 1 : 0;
    }
}

// ---------------------------------------------------------------------------
// Inverted greedy NMS (faithful port). One block per slot, 1024 threads.
// Each step: pick argmax-score alive box (first index on ties), keep it,
// RETAIN only alive boxes with IoU >= 0.5 against it. Early-exit when no
// alive boxes remain (fixed point of the reference scan).
// ---------------------------------------------------------------------------
__global__ __launch_bounds__(1024) void nms_kernel(
    const float* __restrict__ boxes, const float* __restrict__ scores,
    const int* __restrict__ valid, float* __restrict__ keep)
{
    const int slot = blockIdx.x;
    const int base = slot * NCELL;
    __shared__ unsigned char alive[NCELL];
    __shared__ float rv[16];
    __shared__ int   ri[16];
    __shared__ int   spick;
    const int t = threadIdx.x;

    for (int n = t; n < NCELL; n += 1024) {
        alive[n] = (unsigned char)valid[base + n];
        keep[base + n] = 0.f;
    }
    __syncthreads();

    for (;;) {
        // ---- argmax over alive scores (first index wins ties) ----
        float bv = -1e30f;
        int   bi = 0x7fffffff;
        for (int n = t; n < NCELL; n += 1024) {
            if (alive[n]) {
                float v = scores[base + n];
                if (v > bv) { bv = v; bi = n; }   // n increasing => first max kept
            }
        }
#pragma unroll
        for (int o = 32; o > 0; o >>= 1) {
            float ov = __shfl_down(bv, o);
            int   oi = __shfl_down(bi, o);
            if (ov > bv || (ov == bv && oi < bi)) { bv = ov; bi = oi; }
        }
        if ((t & 63) == 0) { rv[t >> 6] = bv; ri[t >> 6] = bi; }
        __syncthreads();
        if (t < 64) {
            float v2 = (t < 16) ? rv[t] : -1e30f;
            int   i2 = (t < 16) ? ri[t] : 0x7fffffff;
#pragma unroll
            for (int o = 8; o > 0; o >>= 1) {
                float ov = __shfl_down(v2, o);
                int   oi = __shfl_down(i2, o);
                if (ov > v2 || (ov == v2 && oi < i2)) { v2 = ov; i2 = oi; }
            }
            if (t == 0) spick = (v2 == -1e30f) ? -1 : i2;
        }
        __syncthreads();
        const int i = spick;
        if (i < 0) break;                       // no alive boxes -> fixed point
        if (t == 0) keep[base + i] = 1.f;

        const float xi1 = boxes[(size_t)(base + i) * 4 + 0];
        const float yi1 = boxes[(size_t)(base + i) * 4 + 1];
        const float xi2 = boxes[(size_t)(base + i) * 4 + 2];
        const float yi2 = boxes[(size_t)(base + i) * 4 + 3];
        const float ai  = (xi2 - xi1) * (yi2 - yi1);

        for (int n = t; n < NCELL; n += 1024) {
            if (alive[n]) {
                float x1 = boxes[(size_t)(base + n) * 4 + 0];
                float y1 = boxes[(size_t)(base + n) * 4 + 1];
                float x2 = boxes[(size_t)(base + n) * 4 + 2];
                float y2 = boxes[(size_t)(base + n) * 4 + 3];
                float an = (x2 - x1) * (y2 - y1);
                float ix1 = fmaxf(x1, xi1);
                float iy1 = fmaxf(y1, yi1);
                float ix2 = fminf(x2, xi2);
                float iy2 = fminf(y2, yi2);
                float inter = fmaxf(ix2 - ix1, 0.f) * fmaxf(iy2 - iy1, 0.f);
                float iou = inter / (ai + an - inter);   // IEEE divide
                alive[n] = (iou >= 0.5f && n != i) ? (unsigned char)1 : (unsigned char)0;
            }
        }
        __syncthreads();
    }
}

// ---------------------------------------------------------------------------
// Pack output: (2, 3136, 25) = [boxes*448, score, labels(20)] * keep
// ---------------------------------------------------------------------------
__global__ void pack_out(const float* __restrict__ act,
                         const float* __restrict__ boxes,
                         const float* __restrict__ scores,
                         const float* __restrict__ keep,
                         float* __restrict__ out)
{
    int idx = blockIdx.x * 256 + threadIdx.x;
    if (idx >= 2 * NCELL * 25) return;
    int c  = idx % 25;
    int sn = idx / 25;           // s*NCELL + n
    int n  = sn % NCELL;
    float k = keep[sn];
    float v;
    if (c < 4)       v = boxes[(size_t)sn * 4 + c] * 448.0f;
    else if (c == 4) v = scores[sn];
    else             v = act[(size_t)n * 30 + 10 + (c - 5)];
    out[idx] = v * k;
}

// ---------------------------------------------------------------------------
extern "C" void kernel_launch(void* const* d_in, const int* in_sizes, int n_in,
                              void* d_out, int out_size, void* d_ws, size_t ws_size,
                              hipStream_t stream)
{
    const float* x = (const float*)d_in[0];
    const float* W = (const float*)d_in[1];
    const float* b = (const float*)d_in[2];
    float* out = (float*)d_out;

    // extra (non-partial) scratch floats:
    // act 94080 + boxes 25088 + scores 6272 + valid 6272 + keep 6272
    const size_t extraFloats = (size_t)B_ * NCOL + (size_t)NCELL * 8 +
                               (size_t)NCELL * 2 + (size_t)NCELL * 2 + (size_t)NCELL * 2;
    // splitK must divide 2304 with chunk % 16 == 0  (i.e. splitK | 144)
    const int cands[9] = {16, 12, 9, 8, 6, 4, 3, 2, 1};
    int splitK = 1;
    for (int ci = 0; ci < 9; ++ci) {
        size_t need = ((size_t)cands[ci] * B_ * CPAD + extraFloats) * 4;
        if (need <= ws_size) { splitK = cands[ci]; break; }
    }

    float* ws       = (float*)d_ws;
    float* partial  = ws;
    float* act      = partial + (size_t)splitK * B_ * CPAD;
    float* boxesBuf = act + (size_t)B_ * NCOL;
    float* scoresBuf = boxesBuf + (size_t)NCELL * 8;
    int*   validBuf  = (int*)(scoresBuf + (size_t)NCELL * 2);
    float* keepBuf   = (float*)(validBuf + (size_t)NCELL * 2);

    const int kChunk = KDIM / splitK;

    hipLaunchKernelGGL(gemm_splitk, dim3(12, splitK), dim3(256), 0, stream,
                       x, W, partial, kChunk);
    hipLaunchKernelGGL(combine_bias, dim3((B_ * NCOL + 255) / 256), dim3(256), 0, stream,
                       partial, b, act, splitK);
    hipLaunchKernelGGL(prep_cells, dim3((NCELL + 255) / 256), dim3(256), 0, stream,
                       act, boxesBuf, scoresBuf, validBuf);
    hipLaunchKernelGGL(nms_kernel, dim3(2), dim3(1024), 0, stream,
                       boxesBuf, scoresBuf, validBuf, keepBuf);
    hipLaunchKernelGGL(pack_out, dim3((2 * NCELL * 25 + 255) / 256), dim3(256), 0, stream,
                       act, boxesBuf, scoresBuf, keepBuf, out);
}

// Round 2
// 41.467 us; speedup vs baseline: 1.0289x; 1.0289x over previous
//
#include <hip/hip_runtime.h>

#define B_     64
#define KDIM   2304
#define NCOL   1470
#define NCELL  3136   // 64 * 7 * 7
#define CPAD   1536   // padded col stride for split-K partials

// ---------------------------------------------------------------------------
// GEMM: partial[by][row][col] = sum_{k in chunk} x[row][k] * W[col][k]
// Grid (12 col-tiles of 128, splitK). Block 256. Micro-tile 8 rows x 4 cols
// (cols strided by 32 so LDS W reads hit all 32 banks exactly once).
// ---------------------------------------------------------------------------
__global__ __launch_bounds__(256) void gemm_splitk(
    const float* __restrict__ x, const float* __restrict__ W,
    float* __restrict__ partial, int kChunk)
{
    __shared__ float sx[16 * 68];    // sx[kk][row0..63], stride 68: writes 2-way, reads broadcast
    __shared__ float sw[16 * 132];   // sw[kk][col0..127], stride 132: writes 2-way, reads conflict-free

    const int t  = threadIdx.x;
    const int c0 = blockIdx.x * 128;
    const int k0 = blockIdx.y * kChunk;
    const int r8 = (t >> 5) << 3;    // 8-row group: 0,8,...,56
    const int cg = t & 31;           // col group: cols cg + {0,32,64,96}

    float acc[8][4];
#pragma unroll
    for (int i = 0; i < 8; ++i)
#pragma unroll
        for (int j = 0; j < 4; ++j) acc[i][j] = 0.f;

    const int stages = kChunk >> 4;
    const int kk0 = t & 15;
    const int g0  = t >> 4;          // 0..15

    for (int s = 0; s < stages; ++s) {
        const int kb = k0 + (s << 4);
#pragma unroll
        for (int p = 0; p < 4; ++p) {
            int row = p * 16 + g0;
            sx[kk0 * 68 + row] = x[row * KDIM + kb + kk0];
        }
#pragma unroll
        for (int p = 0; p < 8; ++p) {
            int col = p * 16 + g0;
            int gc  = c0 + col;
            if (gc >= NCOL) gc = NCOL - 1;   // clamp; garbage cols ignored downstream
            sw[kk0 * 132 + col] = W[(size_t)gc * KDIM + kb + kk0];
        }
        __syncthreads();
#pragma unroll
        for (int kk = 0; kk < 16; ++kk) {
            const float4 a0 = *(const float4*)&sx[kk * 68 + r8];
            const float4 a1 = *(const float4*)&sx[kk * 68 + r8 + 4];
            const float w0 = sw[kk * 132 + cg];
            const float w1 = sw[kk * 132 + cg + 32];
            const float w2 = sw[kk * 132 + cg + 64];
            const float w3 = sw[kk * 132 + cg + 96];
            const float av[8] = {a0.x, a0.y, a0.z, a0.w, a1.x, a1.y, a1.z, a1.w};
#pragma unroll
            for (int i = 0; i < 8; ++i) {
                acc[i][0] = fmaf(av[i], w0, acc[i][0]);
                acc[i][1] = fmaf(av[i], w1, acc[i][1]);
                acc[i][2] = fmaf(av[i], w2, acc[i][2]);
                acc[i][3] = fmaf(av[i], w3, acc[i][3]);
            }
        }
        __syncthreads();
    }

    float* pb = partial + (size_t)blockIdx.y * (B_ * CPAD) + c0 + cg;
#pragma unroll
    for (int i = 0; i < 8; ++i)
#pragma unroll
        for (int p = 0; p < 4; ++p)
            pb[(size_t)(r8 + i) * CPAD + 32 * p] = acc[i][p];
}

// ---------------------------------------------------------------------------
// Fused: split-K combine + bias + per-cell decode.
// Block 256 threads handles 8 cells (8*30 = 240 active sum-threads), then 8
// threads finalize (class argmax, box algebra, score, validity).
// Stores ONLY the 20 label columns (what pack re-reads).
// ---------------------------------------------------------------------------
__global__ __launch_bounds__(256) void combine_prep(
    const float* __restrict__ partial, const float* __restrict__ bias,
    float* __restrict__ labels, float* __restrict__ boxes,
    float* __restrict__ scores, int* __restrict__ valid, int splitK)
{
    __shared__ float sa[8][30];
    const int t    = threadIdx.x;
    const int base = blockIdx.x * 8;     // 392 * 8 == 3136 exactly

    if (t < 240) {
        const int n   = base + t / 30;
        const int col = t % 30;
        const int row = n / 49;                    // 1470/30 = 49 cells per row
        const int cr  = (n % 49) * 30 + col;       // flat output column
        float s = 0.f;
        for (int k = 0; k < splitK; ++k)
            s += partial[(size_t)k * (B_ * CPAD) + (size_t)row * CPAD + cr];
        s += bias[cr];
        sa[t / 30][col] = s;
        if (col >= 10) labels[(size_t)n * 20 + (col - 10)] = s;
    }
    __syncthreads();

    if (t < 8) {
        const int n = base + t;
        const float* a = sa[t];

        float mv = a[10];
        int   mi = 0;
#pragma unroll
        for (int j = 1; j < 20; ++j) {
            float v = a[10 + j];
            if (v > mv) { mv = v; mi = j; }        // strict > => first-index tie-break
        }
        const float lp = (float)mi;

        const int gx = n % 7;
        const int gy = (n / 7) % 7;
        const float cell = (float)(1.0 / 7.0);
        const float nx = (float)gx * cell;
        const float ny = (float)gy * cell;

#pragma unroll
        for (int s = 0; s < 2; ++s) {
            const int off = 5 * s;
            const float bx0 = a[off + 0], bx1 = a[off + 1];
            const float w_  = a[off + 2], h_  = a[off + 3];
            const float sc  = a[off + 5];          // faithful port quirk: off+5
            const float cx = bx0 * cell + nx;
            const float cy = bx1 * cell + ny;
            const float X1 = cx - 0.5f * w_;
            const float Y1 = cy - 0.5f * h_;
            const float X2 = cx + 0.5f * w_;
            const float Y2 = cy + 0.5f * h_;
            const int m = s * NCELL + n;
            boxes[m * 4 + 0] = X1 - 0.5f * X2;
            boxes[m * 4 + 1] = Y1 - 0.5f * Y2;
            boxes[m * 4 + 2] = X1 + 0.5f * X2;
            boxes[m * 4 + 3] = Y1 + 0.5f * Y2;
            scores[m] = sc;
            valid[m]  = (sc * lp > 0.5f) ? 1 : 0;
        }
    }
}

// ---------------------------------------------------------------------------
// Inverted greedy NMS with compacted alive lists in LDS. One block per slot.
// Each step: argmax-score alive box (first index on ties), keep it, RETAIN
// only boxes with IoU >= 0.5 against it. Work per iter ~ alive count.
// ---------------------------------------------------------------------------
__global__ __launch_bounds__(1024) void nms_kernel(
    const float* __restrict__ boxes, const float* __restrict__ scores,
    const int* __restrict__ valid, float* __restrict__ keep)
{
    const int slot = blockIdx.x;
    const int base = slot * NCELL;
    const int t = threadIdx.x;

    __shared__ int lstA[NCELL];
    __shared__ int lstB[NCELL];
    __shared__ int cntA, cntB;
    __shared__ float rv[16];
    __shared__ int   ri[16];
    __shared__ int   spick;

    if (t == 0) { cntA = 0; cntB = 0; }
    __syncthreads();

    for (int n = t; n < NCELL; n += 1024) {
        keep[base + n] = 0.f;
        if (valid[base + n]) {
            int p = atomicAdd(&cntA, 1);
            lstA[p] = n;
        }
    }
    __syncthreads();

    int* cur = lstA; int* nxt = lstB;
    int* curCnt = &cntA; int* nxtCnt = &cntB;

    for (;;) {
        const int cnt = *curCnt;

        // ---- argmax over compacted alive scores (min index wins ties) ----
        float bv = -1e30f;
        int   bi = 0x7fffffff;
        for (int j = t; j < cnt; j += 1024) {
            const int n = cur[j];
            const float v = scores[base + n];
            if (v > bv || (v == bv && n < bi)) { bv = v; bi = n; }
        }
#pragma unroll
        for (int o = 32; o > 0; o >>= 1) {
            const float ov = __shfl_down(bv, o);
            const int   oi = __shfl_down(bi, o);
            if (ov > bv || (ov == bv && oi < bi)) { bv = ov; bi = oi; }
        }
        if ((t & 63) == 0) { rv[t >> 6] = bv; ri[t >> 6] = bi; }
        __syncthreads();
        if (t < 64) {
            float v2 = (t < 16) ? rv[t] : -1e30f;
            int   i2 = (t < 16) ? ri[t] : 0x7fffffff;
#pragma unroll
            for (int o = 8; o > 0; o >>= 1) {
                const float ov = __shfl_down(v2, o);
                const int   oi = __shfl_down(i2, o);
                if (ov > v2 || (ov == v2 && oi < i2)) { v2 = ov; i2 = oi; }
            }
            if (t == 0) {
                spick = (v2 == -1e30f) ? -1 : i2;
                *nxtCnt = 0;
            }
        }
        __syncthreads();
        const int i = spick;
        if (i < 0) break;
        if (t == 0) keep[base + i] = 1.f;

        const float xi1 = boxes[(size_t)(base + i) * 4 + 0];
        const float yi1 = boxes[(size_t)(base + i) * 4 + 1];
        const float xi2 = boxes[(size_t)(base + i) * 4 + 2];
        const float yi2 = boxes[(size_t)(base + i) * 4 + 3];
        const float ai  = (xi2 - xi1) * (yi2 - yi1);

        for (int j = t; j < cnt; j += 1024) {
            const int n = cur[j];
            const float x1 = boxes[(size_t)(base + n) * 4 + 0];
            const float y1 = boxes[(size_t)(base + n) * 4 + 1];
            const float x2 = boxes[(size_t)(base + n) * 4 + 2];
            const float y2 = boxes[(size_t)(base + n) * 4 + 3];
            const float an = (x2 - x1) * (y2 - y1);
            const float ix1 = fmaxf(x1, xi1);
            const float iy1 = fmaxf(y1, yi1);
            const float ix2 = fminf(x2, xi2);
            const float iy2 = fminf(y2, yi2);
            const float inter = fmaxf(ix2 - ix1, 0.f) * fmaxf(iy2 - iy1, 0.f);
            const float iou = inter / (ai + an - inter);   // IEEE divide, as reference
            if (iou >= 0.5f && n != i) {
                int p = atomicAdd(nxtCnt, 1);
                nxt[p] = n;
            }
        }
        __syncthreads();
        { int* tl = cur; cur = nxt; nxt = tl; }
        { int* tc = curCnt; curCnt = nxtCnt; nxtCnt = tc; }
    }
}

// ---------------------------------------------------------------------------
// Pack output: (2, 3136, 25) = [boxes*448, score, labels(20)] * keep
// ---------------------------------------------------------------------------
__global__ void pack_out(const float* __restrict__ labels,
                         const float* __restrict__ boxes,
                         const float* __restrict__ scores,
                         const float* __restrict__ keep,
                         float* __restrict__ out)
{
    int idx = blockIdx.x * 256 + threadIdx.x;
    if (idx >= 2 * NCELL * 25) return;
    int c  = idx % 25;
    int sn = idx / 25;           // s*NCELL + n
    int n  = sn % NCELL;
    float k = keep[sn];
    float v;
    if (c < 4)       v = boxes[(size_t)sn * 4 + c] * 448.0f;
    else if (c == 4) v = scores[sn];
    else             v = labels[(size_t)n * 20 + (c - 5)];
    out[idx] = v * k;
}

// ---------------------------------------------------------------------------
extern "C" void kernel_launch(void* const* d_in, const int* in_sizes, int n_in,
                              void* d_out, int out_size, void* d_ws, size_t ws_size,
                              hipStream_t stream)
{
    const float* x = (const float*)d_in[0];
    const float* W = (const float*)d_in[1];
    const float* b = (const float*)d_in[2];
    float* out = (float*)d_out;

    // extra (non-partial) scratch floats: labels + boxes + scores + valid + keep
    const size_t extraFloats = (size_t)NCELL * 20 + (size_t)NCELL * 8 +
                               (size_t)NCELL * 2 + (size_t)NCELL * 2 + (size_t)NCELL * 2;
    // splitK must divide 144 (kChunk % 16 == 0)
    const int cands[8] = {24, 16, 12, 8, 6, 4, 2, 1};
    int splitK = 1;
    for (int ci = 0; ci < 8; ++ci) {
        size_t need = ((size_t)cands[ci] * B_ * CPAD + extraFloats) * 4;
        if (need <= ws_size) { splitK = cands[ci]; break; }
    }

    float* ws        = (float*)d_ws;
    float* partial   = ws;
    float* labelsBuf = partial + (size_t)splitK * B_ * CPAD;
    float* boxesBuf  = labelsBuf + (size_t)NCELL * 20;
    float* scoresBuf = boxesBuf + (size_t)NCELL * 8;
    int*   validBuf  = (int*)(scoresBuf + (size_t)NCELL * 2);
    float* keepBuf   = (float*)(validBuf + (size_t)NCELL * 2);

    const int kChunk = KDIM / splitK;

    hipLaunchKernelGGL(gemm_splitk, dim3(12, splitK), dim3(256), 0, stream,
                       x, W, partial, kChunk);
    hipLaunchKernelGGL(combine_prep, dim3(NCELL / 8), dim3(256), 0, stream,
                       partial, b, labelsBuf, boxesBuf, scoresBuf, validBuf, splitK);
    hipLaunchKernelGGL(nms_kernel, dim3(2), dim3(1024), 0, stream,
                       boxesBuf, scoresBuf, validBuf, keepBuf);
    hipLaunchKernelGGL(pack_out, dim3((2 * NCELL * 25 + 255) / 256), dim3(256), 0, stream,
                       labelsBuf, boxesBuf, scoresBuf, keepBuf, out);
}